// Round 4
// baseline (14472.736 us; speedup 1.0000x reference)
//
#include <hip/hip_runtime.h>

// Problem constants
#define Bsz 131072
#define Dd  256
#define Ll  4
#define Kk  1024
#define TB  64                 // vectors per workgroup
#define NWG (Bsz / TB)         // 2048

// Output layout (element offsets into float32 d_out, concat in return order)
#define O_IDX   0ULL                                   // indices      [B][L]
#define O_QSTK  524288ULL                              // quant_stack  [B][L][D]
#define O_QSUM  (O_QSTK + (size_t)Bsz * Ll * Dd)       // quant_sum    [B][D]
#define O_QSQ   (O_QSUM + (size_t)Bsz * Dd)            // quant_sum_qs [B][D]
#define O_RES   (O_QSQ  + (size_t)Bsz * Dd)            // res_states   [L+1][B][D]
#define O_LOSS  (O_RES  + (size_t)(Ll + 1) * Bsz * Dd) // 3 scalars

// ws layout (floats): [0, NWG*4) per-WG per-level ssq partials; [8192, +4096) c2
#define WS_C2_OFF 8192

// ---------------------------------------------------------------------------
// numpy-mirror row sum-of-squares for 256 contiguous floats:
//   x = a*a elementwise (rounded), pairwise sum: 256 -> 128+128;
//   per-128: SSE 4-lane x 8 accumulators, combine ((r0+r1)+(r2+r3))+((r4+r5)+(r6+r7)),
//   horizontal (SSE3 hadd): (w0+w1)+(w2+w3); total = blk0 + blk1.
// All ops via _rn intrinsics to forbid contraction/reassociation.
// ---------------------------------------------------------------------------
__device__ __forceinline__ float np_rowsum_sq(const float* a) {
    float blk[2];
    #pragma unroll
    for (int hb = 0; hb < 2; ++hb) {
        const float* p = a + hb * 128;
        float r8[8][4];
        #pragma unroll
        for (int j = 0; j < 8; ++j) {
            float4 x = *(const float4*)(p + 4 * j);
            r8[j][0] = __fmul_rn(x.x, x.x);
            r8[j][1] = __fmul_rn(x.y, x.y);
            r8[j][2] = __fmul_rn(x.z, x.z);
            r8[j][3] = __fmul_rn(x.w, x.w);
        }
        #pragma unroll
        for (int i = 32; i < 128; i += 32) {
            #pragma unroll
            for (int j = 0; j < 8; ++j) {
                float4 x = *(const float4*)(p + i + 4 * j);
                r8[j][0] = __fadd_rn(r8[j][0], __fmul_rn(x.x, x.x));
                r8[j][1] = __fadd_rn(r8[j][1], __fmul_rn(x.y, x.y));
                r8[j][2] = __fadd_rn(r8[j][2], __fmul_rn(x.z, x.z));
                r8[j][3] = __fadd_rn(r8[j][3], __fmul_rn(x.w, x.w));
            }
        }
        float wv[4];
        #pragma unroll
        for (int L = 0; L < 4; ++L) {
            wv[L] = __fadd_rn(
                __fadd_rn(__fadd_rn(r8[0][L], r8[1][L]), __fadd_rn(r8[2][L], r8[3][L])),
                __fadd_rn(__fadd_rn(r8[4][L], r8[5][L]), __fadd_rn(r8[6][L], r8[7][L])));
        }
        blk[hb] = __fadd_rn(__fadd_rn(wv[0], wv[1]), __fadd_rn(wv[2], wv[3]));
    }
    return __fadd_rn(blk[0], blk[1]);
}

// ---------------------------------------------------------------------------
// prep: c2[l*K + k] = np-order sum of squares of codebook row (4096 rows)
// ---------------------------------------------------------------------------
__global__ void prep_kernel(const float* __restrict__ cbks, float* __restrict__ ws) {
    int t = blockIdx.x * 256 + threadIdx.x;
    if (t < Ll * Kk) {
        ws[WS_C2_OFF + t] = np_rowsum_sq(cbks + (size_t)t * Dd);
    }
}

// ---------------------------------------------------------------------------
// main residual-VQ kernel: one workgroup owns 64 vectors for all 4 levels
// ---------------------------------------------------------------------------
__global__ __launch_bounds__(256, 2) void rvq_kernel(
    const float* __restrict__ ze, const float* __restrict__ cbks,
    float* __restrict__ out, float* __restrict__ ws)
{
    __shared__ float rbuf[TB][Dd + 4];   // residual tile, +4 pad (rows 16B aligned)
    __shared__ float r2s[TB];
    __shared__ int   bidx[TB];
    __shared__ float wssq[4];

    const int tid  = threadIdx.x;
    const int wg   = blockIdx.x;
    const int b0   = wg * TB;
    const int lane = tid & 63;
    const int w    = tid >> 6;     // wave id 0..3
    const int tk   = tid & 15;     // code-group lane
    const int tv   = tid >> 4;     // vec-group 0..15
    const int v0   = tv * 4;

    // Load ze tile -> rbuf, and write residual_states[0] = ze
    for (int i = tid; i < TB * Dd / 4; i += 256) {
        int v  = i >> 6;
        int dp = (i & 63) << 2;
        float4 x = *(const float4*)(ze + (size_t)(b0 + v) * Dd + dp);
        *(float4*)&rbuf[v][dp] = x;
        *(float4*)(out + O_RES + (size_t)(b0 + v) * Dd + dp) = x;
    }
    __syncthreads();

    const float* c2 = ws + WS_C2_OFF;

    for (int l = 0; l < Ll; ++l) {
        // ---- r2 per vector, numpy pairwise order (thread t owns vector t) ----
        if (tid < TB) r2s[tid] = np_rowsum_sq(&rbuf[tid][0]);
        __syncthreads();

        const float* cb  = cbks + (size_t)l * Kk * Dd;
        const float* c2l = c2 + l * Kk;

        // ---- scores + running argmin: thread covers 4 vecs x 64 codes ----
        // dot = sequential single-accumulator FMA chain over d (BLAS order)
        float bs[4] = {1e30f, 1e30f, 1e30f, 1e30f};
        int   bi[4] = {0, 0, 0, 0};

        for (int kk = 0; kk < Kk; kk += 64) {
            const int kb = kk + tk * 4;
            const float* cp = cb + (size_t)kb * Dd;

            float acc[4][4];
            #pragma unroll
            for (int vi = 0; vi < 4; ++vi)
                #pragma unroll
                for (int j = 0; j < 4; ++j)
                    acc[vi][j] = 0.f;

            #pragma unroll 2
            for (int d = 0; d < Dd; d += 4) {
                float4 rr[4];
                #pragma unroll
                for (int vi = 0; vi < 4; ++vi)
                    rr[vi] = *(const float4*)&rbuf[v0 + vi][d];
                float4 cc[4];
                #pragma unroll
                for (int j = 0; j < 4; ++j)
                    cc[j] = *(const float4*)(cp + j * Dd + d);
                #pragma unroll
                for (int vi = 0; vi < 4; ++vi) {
                    #pragma unroll
                    for (int j = 0; j < 4; ++j) {
                        float t = acc[vi][j];
                        t = __fmaf_rn(rr[vi].x, cc[j].x, t);
                        t = __fmaf_rn(rr[vi].y, cc[j].y, t);
                        t = __fmaf_rn(rr[vi].z, cc[j].z, t);
                        t = __fmaf_rn(rr[vi].w, cc[j].w, t);
                        acc[vi][j] = t;
                    }
                }
            }

            #pragma unroll
            for (int j = 0; j < 4; ++j) {
                float c2v = c2l[kb + j];
                int   k   = kb + j;
                #pragma unroll
                for (int vi = 0; vi < 4; ++vi) {
                    float t1 = __fadd_rn(r2s[v0 + vi], c2v);
                    float s  = __fsub_rn(t1, 2.0f * acc[vi][j]);
                    if (s < bs[vi]) { bs[vi] = s; bi[vi] = k; }
                }
            }
        }

        // ---- reduce argmin across the 16 tk lanes (tie -> lower index) ----
        #pragma unroll
        for (int m = 1; m < 16; m <<= 1) {
            #pragma unroll
            for (int vi = 0; vi < 4; ++vi) {
                float os = __shfl_xor(bs[vi], m);
                int   oi = __shfl_xor(bi[vi], m);
                if (os < bs[vi] || (os == bs[vi] && oi < bi[vi])) {
                    bs[vi] = os; bi[vi] = oi;
                }
            }
        }
        if (tk == 0) {
            #pragma unroll
            for (int vi = 0; vi < 4; ++vi) {
                bidx[v0 + vi] = bi[vi];
                out[O_IDX + (size_t)(b0 + v0 + vi) * Ll + l] = (float)bi[vi];
            }
        }
        __syncthreads();

        // ---- gather chosen codes, update residual, emit outputs ----
        float ssq = 0.f;
        for (int v = w * 16; v < w * 16 + 16; ++v) {
            int idx = bidx[v];
            const float4 q = *(const float4*)(cb + (size_t)idx * Dd + (lane << 2));
            float4 r = *(const float4*)&rbuf[v][lane << 2];
            float4 nr = make_float4(r.x - q.x, r.y - q.y, r.z - q.z, r.w - q.w);
            *(float4*)&rbuf[v][lane << 2] = nr;
            size_t gb = (size_t)(b0 + v);
            *(float4*)(out + O_QSTK + ((gb * Ll) + l) * Dd + (lane << 2)) = q;
            *(float4*)(out + O_RES + ((size_t)(l + 1) * Bsz + gb) * Dd + (lane << 2)) = nr;
            ssq += nr.x * nr.x + nr.y * nr.y + nr.z * nr.z + nr.w * nr.w;
        }
        #pragma unroll
        for (int m = 32; m; m >>= 1) ssq += __shfl_xor(ssq, m);
        if (lane == 0) wssq[w] = ssq;
        __syncthreads();
        if (tid == 0) ws[wg * 4 + l] = wssq[0] + wssq[1] + wssq[2] + wssq[3];
    }

    // ---- quantized_sum = ze - final_residual; qspace = ze + (qsum - ze) ----
    for (int i = tid; i < TB * Dd / 4; i += 256) {
        int v  = i >> 6;
        int dp = (i & 63) << 2;
        size_t gb = (size_t)(b0 + v);
        float4 z = *(const float4*)(ze + gb * Dd + dp);
        float4 r = *(const float4*)&rbuf[v][dp];
        float4 qs = make_float4(z.x - r.x, z.y - r.y, z.z - r.z, z.w - r.w);
        *(float4*)(out + O_QSUM + gb * Dd + dp) = qs;
        float4 qq = make_float4(z.x + (qs.x - z.x), z.y + (qs.y - z.y),
                                z.z + (qs.z - z.z), z.w + (qs.w - z.w));
        *(float4*)(out + O_QSQ + gb * Dd + dp) = qq;
    }
}

// ---------------------------------------------------------------------------
// loss: deterministic reduction of per-WG partials -> 3 scalars
// ---------------------------------------------------------------------------
__global__ void loss_kernel(const float* __restrict__ ws, float* __restrict__ out) {
    __shared__ float red[Ll * 4];
    int tid = threadIdx.x;
    int lane = tid & 63, w = tid >> 6;
    for (int l = 0; l < Ll; ++l) {
        float s = 0.f;
        for (int i = tid; i < NWG; i += 256) s += ws[i * 4 + l];
        #pragma unroll
        for (int m = 32; m; m >>= 1) s += __shfl_xor(s, m);
        if (lane == 0) red[l * 4 + w] = s;
    }
    __syncthreads();
    if (tid == 0) {
        float tot = 0.f;
        for (int l = 0; l < Ll; ++l)
            tot += red[l * 4 + 0] + red[l * 4 + 1] + red[l * 4 + 2] + red[l * 4 + 3];
        float cm = tot / (float)((size_t)Ll * Bsz * Dd);
        out[O_LOSS + 0] = cm;                    // commitment_loss
        out[O_LOSS + 1] = cm;                    // codebook_loss
        out[O_LOSS + 2] = 0.25f * cm + cm;       // quantization_loss
    }
}

extern "C" void kernel_launch(void* const* d_in, const int* in_sizes, int n_in,
                              void* d_out, int out_size, void* d_ws, size_t ws_size,
                              hipStream_t stream) {
    (void)in_sizes; (void)n_in; (void)out_size; (void)ws_size;
    const float* ze   = (const float*)d_in[0];
    const float* cbks = (const float*)d_in[1];
    float* out = (float*)d_out;
    float* ws  = (float*)d_ws;

    hipLaunchKernelGGL(prep_kernel, dim3(16), dim3(256), 0, stream, cbks, ws);
    hipLaunchKernelGGL(rvq_kernel, dim3(NWG), dim3(256), 0, stream, ze, cbks, out, ws);
    hipLaunchKernelGGL(loss_kernel, dim3(1), dim3(256), 0, stream, ws, out);
}

// Round 5
// 7499.552 us; speedup vs baseline: 1.9298x; 1.9298x over previous
//
#include <hip/hip_runtime.h>

// Problem constants
#define Bsz 131072
#define Dd  256
#define Ll  4
#define Kk  1024
#define TB  32                 // vectors per workgroup
#define NWG (Bsz / TB)         // 4096

// Output layout (element offsets into float32 d_out, concat in return order)
#define O_IDX   0ULL                                   // indices      [B][L]
#define O_QSTK  524288ULL                              // quant_stack  [B][L][D]
#define O_QSUM  (O_QSTK + (size_t)Bsz * Ll * Dd)       // quant_sum    [B][D]
#define O_QSQ   (O_QSUM + (size_t)Bsz * Dd)            // quant_sum_qs [B][D]
#define O_RES   (O_QSQ  + (size_t)Bsz * Dd)            // res_states   [L+1][B][D]
#define O_LOSS  (O_RES  + (size_t)(Ll + 1) * Bsz * Dd) // 3 scalars

// ws layout (float elements):
//   [0, 16384)        per-WG per-level ssq partials (NWG*4)
//   [16384, 20480)    c2 (L*K)
//   [32768, +1048576) CB_T[l][d][k]  (transposed codebook, 4 MB)
#define WS_C2_OFF  16384
#define WS_CBT_OFF 32768

// ---------------------------------------------------------------------------
// numpy-mirror row sum-of-squares for 256 contiguous floats (pairwise order).
// ---------------------------------------------------------------------------
__device__ __forceinline__ float np_rowsum_sq(const float* a) {
    float blk[2];
    #pragma unroll
    for (int hb = 0; hb < 2; ++hb) {
        const float* p = a + hb * 128;
        float r8[8][4];
        #pragma unroll
        for (int j = 0; j < 8; ++j) {
            float4 x = *(const float4*)(p + 4 * j);
            r8[j][0] = __fmul_rn(x.x, x.x);
            r8[j][1] = __fmul_rn(x.y, x.y);
            r8[j][2] = __fmul_rn(x.z, x.z);
            r8[j][3] = __fmul_rn(x.w, x.w);
        }
        #pragma unroll
        for (int i = 32; i < 128; i += 32) {
            #pragma unroll
            for (int j = 0; j < 8; ++j) {
                float4 x = *(const float4*)(p + i + 4 * j);
                r8[j][0] = __fadd_rn(r8[j][0], __fmul_rn(x.x, x.x));
                r8[j][1] = __fadd_rn(r8[j][1], __fmul_rn(x.y, x.y));
                r8[j][2] = __fadd_rn(r8[j][2], __fmul_rn(x.z, x.z));
                r8[j][3] = __fadd_rn(r8[j][3], __fmul_rn(x.w, x.w));
            }
        }
        float wv[4];
        #pragma unroll
        for (int L = 0; L < 4; ++L) {
            wv[L] = __fadd_rn(
                __fadd_rn(__fadd_rn(r8[0][L], r8[1][L]), __fadd_rn(r8[2][L], r8[3][L])),
                __fadd_rn(__fadd_rn(r8[4][L], r8[5][L]), __fadd_rn(r8[6][L], r8[7][L])));
        }
        blk[hb] = __fadd_rn(__fadd_rn(wv[0], wv[1]), __fadd_rn(wv[2], wv[3]));
    }
    return __fadd_rn(blk[0], blk[1]);
}

// ---------------------------------------------------------------------------
// prep: c2[l*K + k] = np-order sum of squares of codebook row
// ---------------------------------------------------------------------------
__global__ void prep_kernel(const float* __restrict__ cbks, float* __restrict__ ws) {
    int t = blockIdx.x * 256 + threadIdx.x;
    if (t < Ll * Kk) {
        ws[WS_C2_OFF + t] = np_rowsum_sq(cbks + (size_t)t * Dd);
    }
}

// ---------------------------------------------------------------------------
// transpose: CB_T[l][d][k] = cbks[l][k][d]   (one block per (l,d) row)
// ---------------------------------------------------------------------------
__global__ void transpose_kernel(const float* __restrict__ cbks, float* __restrict__ ws) {
    int ld = blockIdx.x;               // 0 .. L*D-1
    int l  = ld >> 8, d = ld & 255;
    const float* src = cbks + (size_t)l * Kk * Dd + d;
    float* dst = ws + WS_CBT_OFF + (size_t)ld * Kk;
    int k = threadIdx.x;
    #pragma unroll
    for (int kk = 0; kk < Kk; kk += 256)
        dst[kk + k] = src[(size_t)(kk + k) * Dd];
}

// ---------------------------------------------------------------------------
// main residual-VQ kernel: one workgroup owns 32 vectors for all 4 levels
// thread = (tv 0..15, tk 0..15): 2 vecs x 8 codes per kk-block (128 codes)
// ---------------------------------------------------------------------------
__global__ __launch_bounds__(256, 4) void rvq_kernel(
    const float* __restrict__ ze, const float* __restrict__ cbks,
    float* __restrict__ out, float* __restrict__ ws)
{
    __shared__ float rbuf[TB][Dd + 4];   // 33.3 KB, +4 pad (rows land on distinct banks)
    __shared__ float r2s[TB];
    __shared__ int   bidx[TB];
    __shared__ float wssq[4];

    const int tid  = threadIdx.x;
    const int wg   = blockIdx.x;
    const int b0   = wg * TB;
    const int lane = tid & 63;
    const int w    = tid >> 6;     // wave id 0..3
    const int tk   = tid & 15;     // code-group lane
    const int tv   = tid >> 4;     // vec-group 0..15
    const int v0   = tv * 2;

    // Load ze tile -> rbuf, and write residual_states[0] = ze
    for (int i = tid; i < TB * Dd / 4; i += 256) {
        int v  = i >> 6;
        int dp = (i & 63) << 2;
        float4 x = *(const float4*)(ze + (size_t)(b0 + v) * Dd + dp);
        *(float4*)&rbuf[v][dp] = x;
        *(float4*)(out + O_RES + (size_t)(b0 + v) * Dd + dp) = x;
    }
    __syncthreads();

    const float* c2  = ws + WS_C2_OFF;
    const float* cbt = ws + WS_CBT_OFF;

    for (int l = 0; l < Ll; ++l) {
        // ---- r2 per vector, numpy pairwise order ----
        if (tid < TB) r2s[tid] = np_rowsum_sq(&rbuf[tid][0]);
        __syncthreads();

        const float* cb   = cbks + (size_t)l * Kk * Dd;     // row-major (gather)
        const float* ctl  = cbt + (size_t)l * Dd * Kk;      // [d][k] (scores)
        const float* c2l  = c2 + l * Kk;

        // ---- scores + running argmin: thread covers 2 vecs x 8 codes ----
        float bs[2] = {1e30f, 1e30f};
        int   bi[2] = {0, 0};

        for (int kk = 0; kk < Kk; kk += 128) {
            __syncthreads();             // keep waves lockstep -> L1 merges streams
            const int kb = kk + tk * 8;
            const float* crow = ctl + kb;

            float acc[2][8];
            #pragma unroll
            for (int vi = 0; vi < 2; ++vi)
                #pragma unroll
                for (int c = 0; c < 8; ++c)
                    acc[vi][c] = 0.f;

            #pragma unroll 2
            for (int d = 0; d < Dd; d += 4) {
                // residual: 2 rows x 4 dims (LDS broadcast within 16-lane groups)
                float4 r4[2];
                r4[0] = *(const float4*)&rbuf[v0][d];
                r4[1] = *(const float4*)&rbuf[v0 + 1][d];
                float rs[4][2];
                rs[0][0] = r4[0].x; rs[1][0] = r4[0].y; rs[2][0] = r4[0].z; rs[3][0] = r4[0].w;
                rs[0][1] = r4[1].x; rs[1][1] = r4[1].y; rs[2][1] = r4[1].z; rs[3][1] = r4[1].w;
                // codebook: 4 d-rows x 8 codes, coalesced along k
                float cs[4][8];
                #pragma unroll
                for (int i = 0; i < 4; ++i) {
                    float4 a = *(const float4*)(crow + ((size_t)(d + i) << 10));
                    float4 b = *(const float4*)(crow + ((size_t)(d + i) << 10) + 4);
                    cs[i][0] = a.x; cs[i][1] = a.y; cs[i][2] = a.z; cs[i][3] = a.w;
                    cs[i][4] = b.x; cs[i][5] = b.y; cs[i][6] = b.z; cs[i][7] = b.w;
                }
                // sequential FMA chains (d ascending within each chain)
                #pragma unroll
                for (int vi = 0; vi < 2; ++vi) {
                    #pragma unroll
                    for (int c = 0; c < 8; ++c) {
                        float t = acc[vi][c];
                        t = __fmaf_rn(rs[0][vi], cs[0][c], t);
                        t = __fmaf_rn(rs[1][vi], cs[1][c], t);
                        t = __fmaf_rn(rs[2][vi], cs[2][c], t);
                        t = __fmaf_rn(rs[3][vi], cs[3][c], t);
                        acc[vi][c] = t;
                    }
                }
            }

            // scores + running argmin (codes ascending: strict < keeps lowest)
            #pragma unroll
            for (int c = 0; c < 8; ++c) {
                float c2v = c2l[kb + c];
                int   k   = kb + c;
                #pragma unroll
                for (int vi = 0; vi < 2; ++vi) {
                    float t1 = __fadd_rn(r2s[v0 + vi], c2v);
                    float s  = __fsub_rn(t1, 2.0f * acc[vi][c]);
                    if (s < bs[vi]) { bs[vi] = s; bi[vi] = k; }
                }
            }
        }

        // ---- reduce argmin across the 16 tk lanes (tie -> lower index) ----
        #pragma unroll
        for (int m = 1; m < 16; m <<= 1) {
            #pragma unroll
            for (int vi = 0; vi < 2; ++vi) {
                float os = __shfl_xor(bs[vi], m);
                int   oi = __shfl_xor(bi[vi], m);
                if (os < bs[vi] || (os == bs[vi] && oi < bi[vi])) {
                    bs[vi] = os; bi[vi] = oi;
                }
            }
        }
        if (tk == 0) {
            #pragma unroll
            for (int vi = 0; vi < 2; ++vi) {
                bidx[v0 + vi] = bi[vi];
                out[O_IDX + (size_t)(b0 + v0 + vi) * Ll + l] = (float)bi[vi];
            }
        }
        __syncthreads();

        // ---- gather chosen codes, update residual, emit outputs ----
        float ssq = 0.f;
        for (int v = w * 8; v < w * 8 + 8; ++v) {
            int idx = bidx[v];
            const float4 q = *(const float4*)(cb + (size_t)idx * Dd + (lane << 2));
            float4 r = *(const float4*)&rbuf[v][lane << 2];
            float4 nr = make_float4(r.x - q.x, r.y - q.y, r.z - q.z, r.w - q.w);
            *(float4*)&rbuf[v][lane << 2] = nr;
            size_t gb = (size_t)(b0 + v);
            *(float4*)(out + O_QSTK + ((gb * Ll) + l) * Dd + (lane << 2)) = q;
            *(float4*)(out + O_RES + ((size_t)(l + 1) * Bsz + gb) * Dd + (lane << 2)) = nr;
            ssq += nr.x * nr.x + nr.y * nr.y + nr.z * nr.z + nr.w * nr.w;
        }
        #pragma unroll
        for (int m = 32; m; m >>= 1) ssq += __shfl_xor(ssq, m);
        if (lane == 0) wssq[w] = ssq;
        __syncthreads();
        if (tid == 0) ws[wg * 4 + l] = wssq[0] + wssq[1] + wssq[2] + wssq[3];
    }

    // ---- quantized_sum = ze - final_residual; qspace = ze + (qsum - ze) ----
    for (int i = tid; i < TB * Dd / 4; i += 256) {
        int v  = i >> 6;
        int dp = (i & 63) << 2;
        size_t gb = (size_t)(b0 + v);
        float4 z = *(const float4*)(ze + gb * Dd + dp);
        float4 r = *(const float4*)&rbuf[v][dp];
        float4 qs = make_float4(z.x - r.x, z.y - r.y, z.z - r.z, z.w - r.w);
        *(float4*)(out + O_QSUM + gb * Dd + dp) = qs;
        float4 qq = make_float4(z.x + (qs.x - z.x), z.y + (qs.y - z.y),
                                z.z + (qs.z - z.z), z.w + (qs.w - z.w));
        *(float4*)(out + O_QSQ + gb * Dd + dp) = qq;
    }
}

// ---------------------------------------------------------------------------
// loss: deterministic reduction of per-WG partials -> 3 scalars
// ---------------------------------------------------------------------------
__global__ void loss_kernel(const float* __restrict__ ws, float* __restrict__ out) {
    __shared__ float red[Ll * 4];
    int tid = threadIdx.x;
    int lane = tid & 63, w = tid >> 6;
    for (int l = 0; l < Ll; ++l) {
        float s = 0.f;
        for (int i = tid; i < NWG; i += 256) s += ws[i * 4 + l];
        #pragma unroll
        for (int m = 32; m; m >>= 1) s += __shfl_xor(s, m);
        if (lane == 0) red[l * 4 + w] = s;
    }
    __syncthreads();
    if (tid == 0) {
        float tot = 0.f;
        for (int l = 0; l < Ll; ++l)
            tot += red[l * 4 + 0] + red[l * 4 + 1] + red[l * 4 + 2] + red[l * 4 + 3];
        float cm = tot / (float)((size_t)Ll * Bsz * Dd);
        out[O_LOSS + 0] = cm;                    // commitment_loss
        out[O_LOSS + 1] = cm;                    // codebook_loss
        out[O_LOSS + 2] = 0.25f * cm + cm;       // quantization_loss
    }
}

extern "C" void kernel_launch(void* const* d_in, const int* in_sizes, int n_in,
                              void* d_out, int out_size, void* d_ws, size_t ws_size,
                              hipStream_t stream) {
    (void)in_sizes; (void)n_in; (void)out_size; (void)ws_size;
    const float* ze   = (const float*)d_in[0];
    const float* cbks = (const float*)d_in[1];
    float* out = (float*)d_out;
    float* ws  = (float*)d_ws;

    hipLaunchKernelGGL(prep_kernel, dim3(16), dim3(256), 0, stream, cbks, ws);
    hipLaunchKernelGGL(transpose_kernel, dim3(Ll * Dd), dim3(256), 0, stream, cbks, ws);
    hipLaunchKernelGGL(rvq_kernel, dim3(NWG), dim3(256), 0, stream, ze, cbks, out, ws);
    hipLaunchKernelGGL(loss_kernel, dim3(1), dim3(256), 0, stream, ws, out);
}

// Round 6
// 4792.509 us; speedup vs baseline: 3.0199x; 1.5648x over previous
//
#include <hip/hip_runtime.h>

// Problem constants
#define Bsz 131072
#define Dd  256
#define Ll  4
#define Kk  1024
#define TB  32                 // vectors per workgroup
#define NWG (Bsz / TB)         // 4096

// Output layout (element offsets into float32 d_out, concat in return order)
#define O_IDX   0ULL                                   // indices      [B][L]
#define O_QSTK  524288ULL                              // quant_stack  [B][L][D]
#define O_QSUM  (O_QSTK + (size_t)Bsz * Ll * Dd)       // quant_sum    [B][D]
#define O_QSQ   (O_QSUM + (size_t)Bsz * Dd)            // quant_sum_qs [B][D]
#define O_RES   (O_QSQ  + (size_t)Bsz * Dd)            // res_states   [L+1][B][D]
#define O_LOSS  (O_RES  + (size_t)(Ll + 1) * Bsz * Dd) // 3 scalars

// ws layout (float elements):
//   [0, 16384)        per-WG per-level ssq partials (NWG*4)
//   [16384, 20480)    c2 (L*K)
//   [32768, +1048576) CB_T[l][d][k]  (transposed codebook, 4 MB)
#define WS_C2_OFF  16384
#define WS_CBT_OFF 32768

typedef float v2f __attribute__((ext_vector_type(2)));

// Packed IEEE-rn fp32 FMA, broadcasting one 32-bit half of the R pair:
//  LO: both halves use R.lo ; HI: both halves use R.hi.  Chains stay
//  sequential per code -> bit-identical to scalar __fmaf_rn chains.
#define PKFMA_LO(A, R, C) \
    asm("v_pk_fma_f32 %0, %1, %2, %0 op_sel_hi:[0,1,1]" : "+v"(A) : "v"(R), "v"(C))
#define PKFMA_HI(A, R, C) \
    asm("v_pk_fma_f32 %0, %1, %2, %0 op_sel:[1,0,0]" : "+v"(A) : "v"(R), "v"(C))

// ---------------------------------------------------------------------------
// numpy-mirror row sum-of-squares for 256 contiguous floats (pairwise order).
// ---------------------------------------------------------------------------
__device__ __forceinline__ float np_rowsum_sq(const float* a) {
    float blk[2];
    #pragma unroll
    for (int hb = 0; hb < 2; ++hb) {
        const float* p = a + hb * 128;
        float r8[8][4];
        #pragma unroll
        for (int j = 0; j < 8; ++j) {
            float4 x = *(const float4*)(p + 4 * j);
            r8[j][0] = __fmul_rn(x.x, x.x);
            r8[j][1] = __fmul_rn(x.y, x.y);
            r8[j][2] = __fmul_rn(x.z, x.z);
            r8[j][3] = __fmul_rn(x.w, x.w);
        }
        #pragma unroll
        for (int i = 32; i < 128; i += 32) {
            #pragma unroll
            for (int j = 0; j < 8; ++j) {
                float4 x = *(const float4*)(p + i + 4 * j);
                r8[j][0] = __fadd_rn(r8[j][0], __fmul_rn(x.x, x.x));
                r8[j][1] = __fadd_rn(r8[j][1], __fmul_rn(x.y, x.y));
                r8[j][2] = __fadd_rn(r8[j][2], __fmul_rn(x.z, x.z));
                r8[j][3] = __fadd_rn(r8[j][3], __fmul_rn(x.w, x.w));
            }
        }
        float wv[4];
        #pragma unroll
        for (int L = 0; L < 4; ++L) {
            wv[L] = __fadd_rn(
                __fadd_rn(__fadd_rn(r8[0][L], r8[1][L]), __fadd_rn(r8[2][L], r8[3][L])),
                __fadd_rn(__fadd_rn(r8[4][L], r8[5][L]), __fadd_rn(r8[6][L], r8[7][L])));
        }
        blk[hb] = __fadd_rn(__fadd_rn(wv[0], wv[1]), __fadd_rn(wv[2], wv[3]));
    }
    return __fadd_rn(blk[0], blk[1]);
}

// ---------------------------------------------------------------------------
// prep: c2[l*K + k] = np-order sum of squares of codebook row
// ---------------------------------------------------------------------------
__global__ void prep_kernel(const float* __restrict__ cbks, float* __restrict__ ws) {
    int t = blockIdx.x * 256 + threadIdx.x;
    if (t < Ll * Kk) {
        ws[WS_C2_OFF + t] = np_rowsum_sq(cbks + (size_t)t * Dd);
    }
}

// ---------------------------------------------------------------------------
// transpose: CB_T[l][d][k] = cbks[l][k][d]   (one block per (l,d) row)
// ---------------------------------------------------------------------------
__global__ void transpose_kernel(const float* __restrict__ cbks, float* __restrict__ ws) {
    int ld = blockIdx.x;               // 0 .. L*D-1
    int l  = ld >> 8, d = ld & 255;
    const float* src = cbks + (size_t)l * Kk * Dd + d;
    float* dst = ws + WS_CBT_OFF + (size_t)ld * Kk;
    int k = threadIdx.x;
    #pragma unroll
    for (int kk = 0; kk < Kk; kk += 256)
        dst[kk + k] = src[(size_t)(kk + k) * Dd];
}

// ---------------------------------------------------------------------------
// main residual-VQ kernel: one workgroup owns 32 vectors for all 4 levels
// thread = (tv 0..7, tk 0..31): 4 vecs x 4 codes per kk-block (128 codes)
// packed fp32 FMA, register-double-buffered operands
// ---------------------------------------------------------------------------
__global__ __launch_bounds__(256, 4) void rvq_kernel(
    const float* __restrict__ ze, const float* __restrict__ cbks,
    float* __restrict__ out, float* __restrict__ ws)
{
    __shared__ float rbuf[TB][Dd + 4];   // 33.3 KB
    __shared__ float r2s[TB];
    __shared__ int   bidx[TB];
    __shared__ float wssq[4];

    const int tid  = threadIdx.x;
    const int wg   = blockIdx.x;
    const int b0   = wg * TB;
    const int lane = tid & 63;
    const int w    = tid >> 6;     // wave id 0..3
    const int tk   = tid & 31;     // code-group lane (32)
    const int tv   = tid >> 5;     // vec-group 0..7
    const int v0   = tv * 4;

    // Load ze tile -> rbuf, and write residual_states[0] = ze
    for (int i = tid; i < TB * Dd / 4; i += 256) {
        int v  = i >> 6;
        int dp = (i & 63) << 2;
        float4 x = *(const float4*)(ze + (size_t)(b0 + v) * Dd + dp);
        *(float4*)&rbuf[v][dp] = x;
        *(float4*)(out + O_RES + (size_t)(b0 + v) * Dd + dp) = x;
    }
    __syncthreads();

    const float* c2  = ws + WS_C2_OFF;
    const float* cbt = ws + WS_CBT_OFF;

    for (int l = 0; l < Ll; ++l) {
        // ---- r2 per vector, numpy pairwise order ----
        if (tid < TB) r2s[tid] = np_rowsum_sq(&rbuf[tid][0]);
        __syncthreads();

        const float* cb   = cbks + (size_t)l * Kk * Dd;     // row-major (gather)
        const float* ctl  = cbt + (size_t)l * Dd * Kk;      // [d][k] (scores)
        const float* c2l  = c2 + l * Kk;

        float bs[4] = {1e30f, 1e30f, 1e30f, 1e30f};
        int   bi[4] = {0, 0, 0, 0};

        for (int kk = 0; kk < Kk; kk += 128) {
            __syncthreads();             // keep block's waves on the same k-slab
            const int kb = kk + tk * 4;
            const float* cl0 = ctl + kb;

            v2f acc[4][2];
            #pragma unroll
            for (int vi = 0; vi < 4; ++vi) {
                acc[vi][0] = (v2f)(0.f);
                acc[vi][1] = (v2f)(0.f);
            }

            v2f cA[4][2], cB[4][2], rA[4][2], rB[4][2];

            auto LOADC = [&](v2f (&buf)[4][2], int dd) {
                #pragma unroll
                for (int i = 0; i < 4; ++i) {
                    const float* rp = cl0 + ((size_t)(dd + i) << 10);
                    buf[i][0] = *(const v2f*)rp;
                    buf[i][1] = *(const v2f*)(rp + 2);
                }
            };
            auto LOADR = [&](v2f (&buf)[4][2], int dd) {
                #pragma unroll
                for (int vi = 0; vi < 4; ++vi) {
                    buf[vi][0] = *(const v2f*)&rbuf[v0 + vi][dd];
                    buf[vi][1] = *(const v2f*)&rbuf[v0 + vi][dd + 2];
                }
            };
            auto FMA4 = [&](v2f (&c)[4][2], v2f (&r)[4][2]) {
                #pragma unroll
                for (int vi = 0; vi < 4; ++vi) {
                    #pragma unroll
                    for (int p = 0; p < 2; ++p) {
                        PKFMA_LO(acc[vi][p], r[vi][0], c[0][p]);  // d+0
                        PKFMA_HI(acc[vi][p], r[vi][0], c[1][p]);  // d+1
                        PKFMA_LO(acc[vi][p], r[vi][1], c[2][p]);  // d+2
                        PKFMA_HI(acc[vi][p], r[vi][1], c[3][p]);  // d+3
                    }
                }
            };

            // software-pipelined d-loop: load next 4-d slab while FMA-ing current
            LOADC(cA, 0); LOADR(rA, 0);
            for (int d = 0; d < Dd; d += 8) {
                int dB = (d + 4) & 255;
                LOADC(cB, dB); LOADR(rB, dB);
                FMA4(cA, rA);
                int dA = (d + 8) & 255;   // wraps to 0 on last iter (dummy prefetch)
                LOADC(cA, dA); LOADR(rA, dA);
                FMA4(cB, rB);
            }

            // scores + running argmin (codes ascending: strict < keeps lowest)
            #pragma unroll
            for (int c = 0; c < 4; ++c) {
                float c2v = c2l[kb + c];
                int   k   = kb + c;
                #pragma unroll
                for (int vi = 0; vi < 4; ++vi) {
                    float dotv = acc[vi][c >> 1][c & 1];
                    float t1 = __fadd_rn(r2s[v0 + vi], c2v);
                    float s  = __fsub_rn(t1, 2.0f * dotv);
                    if (s < bs[vi]) { bs[vi] = s; bi[vi] = k; }
                }
            }
        }

        // ---- reduce argmin across the 32 tk lanes (tie -> lower index) ----
        #pragma unroll
        for (int m = 1; m < 32; m <<= 1) {
            #pragma unroll
            for (int vi = 0; vi < 4; ++vi) {
                float os = __shfl_xor(bs[vi], m);
                int   oi = __shfl_xor(bi[vi], m);
                if (os < bs[vi] || (os == bs[vi] && oi < bi[vi])) {
                    bs[vi] = os; bi[vi] = oi;
                }
            }
        }
        if (tk == 0) {
            #pragma unroll
            for (int vi = 0; vi < 4; ++vi) {
                bidx[v0 + vi] = bi[vi];
                out[O_IDX + (size_t)(b0 + v0 + vi) * Ll + l] = (float)bi[vi];
            }
        }
        __syncthreads();

        // ---- gather chosen codes, update residual, emit outputs ----
        float ssq = 0.f;
        for (int v = w * 8; v < w * 8 + 8; ++v) {
            int idx = bidx[v];
            const float4 q = *(const float4*)(cb + (size_t)idx * Dd + (lane << 2));
            float4 r = *(const float4*)&rbuf[v][lane << 2];
            float4 nr = make_float4(r.x - q.x, r.y - q.y, r.z - q.z, r.w - q.w);
            *(float4*)&rbuf[v][lane << 2] = nr;
            size_t gb = (size_t)(b0 + v);
            *(float4*)(out + O_QSTK + ((gb * Ll) + l) * Dd + (lane << 2)) = q;
            *(float4*)(out + O_RES + ((size_t)(l + 1) * Bsz + gb) * Dd + (lane << 2)) = nr;
            ssq += nr.x * nr.x + nr.y * nr.y + nr.z * nr.z + nr.w * nr.w;
        }
        #pragma unroll
        for (int m = 32; m; m >>= 1) ssq += __shfl_xor(ssq, m);
        if (lane == 0) wssq[w] = ssq;
        __syncthreads();
        if (tid == 0) ws[wg * 4 + l] = wssq[0] + wssq[1] + wssq[2] + wssq[3];
    }

    // ---- quantized_sum = ze - final_residual; qspace = ze + (qsum - ze) ----
    for (int i = tid; i < TB * Dd / 4; i += 256) {
        int v  = i >> 6;
        int dp = (i & 63) << 2;
        size_t gb = (size_t)(b0 + v);
        float4 z = *(const float4*)(ze + gb * Dd + dp);
        float4 r = *(const float4*)&rbuf[v][dp];
        float4 qs = make_float4(z.x - r.x, z.y - r.y, z.z - r.z, z.w - r.w);
        *(float4*)(out + O_QSUM + gb * Dd + dp) = qs;
        float4 qq = make_float4(z.x + (qs.x - z.x), z.y + (qs.y - z.y),
                                z.z + (qs.z - z.z), z.w + (qs.w - z.w));
        *(float4*)(out + O_QSQ + gb * Dd + dp) = qq;
    }
}

// ---------------------------------------------------------------------------
// loss: deterministic reduction of per-WG partials -> 3 scalars
// ---------------------------------------------------------------------------
__global__ void loss_kernel(const float* __restrict__ ws, float* __restrict__ out) {
    __shared__ float red[Ll * 4];
    int tid = threadIdx.x;
    int lane = tid & 63, w = tid >> 6;
    for (int l = 0; l < Ll; ++l) {
        float s = 0.f;
        for (int i = tid; i < NWG; i += 256) s += ws[i * 4 + l];
        #pragma unroll
        for (int m = 32; m; m >>= 1) s += __shfl_xor(s, m);
        if (lane == 0) red[l * 4 + w] = s;
    }
    __syncthreads();
    if (tid == 0) {
        float tot = 0.f;
        for (int l = 0; l < Ll; ++l)
            tot += red[l * 4 + 0] + red[l * 4 + 1] + red[l * 4 + 2] + red[l * 4 + 3];
        float cm = tot / (float)((size_t)Ll * Bsz * Dd);
        out[O_LOSS + 0] = cm;                    // commitment_loss
        out[O_LOSS + 1] = cm;                    // codebook_loss
        out[O_LOSS + 2] = 0.25f * cm + cm;       // quantization_loss
    }
}

extern "C" void kernel_launch(void* const* d_in, const int* in_sizes, int n_in,
                              void* d_out, int out_size, void* d_ws, size_t ws_size,
                              hipStream_t stream) {
    (void)in_sizes; (void)n_in; (void)out_size; (void)ws_size;
    const float* ze   = (const float*)d_in[0];
    const float* cbks = (const float*)d_in[1];
    float* out = (float*)d_out;
    float* ws  = (float*)d_ws;

    hipLaunchKernelGGL(prep_kernel, dim3(16), dim3(256), 0, stream, cbks, ws);
    hipLaunchKernelGGL(transpose_kernel, dim3(Ll * Dd), dim3(256), 0, stream, cbks, ws);
    hipLaunchKernelGGL(rvq_kernel, dim3(NWG), dim3(256), 0, stream, ze, cbks, out, ws);
    hipLaunchKernelGGL(loss_kernel, dim3(1), dim3(256), 0, stream, ws, out);
}

// Round 7
// 4609.970 us; speedup vs baseline: 3.1394x; 1.0396x over previous
//
#include <hip/hip_runtime.h>

// Problem constants
#define Bsz 131072
#define Dd  256
#define Ll  4
#define Kk  1024
#define TB  32                 // vectors per workgroup
#define NWG (Bsz / TB)         // 4096

// Output layout (element offsets into float32 d_out, concat in return order)
#define O_IDX   0ULL                                   // indices      [B][L]
#define O_QSTK  524288ULL                              // quant_stack  [B][L][D]
#define O_QSUM  (O_QSTK + (size_t)Bsz * Ll * Dd)       // quant_sum    [B][D]
#define O_QSQ   (O_QSUM + (size_t)Bsz * Dd)            // quant_sum_qs [B][D]
#define O_RES   (O_QSQ  + (size_t)Bsz * Dd)            // res_states   [L+1][B][D]
#define O_LOSS  (O_RES  + (size_t)(Ll + 1) * Bsz * Dd) // 3 scalars

// ws layout (float elements):
//   [0, 16384)        per-WG per-level ssq partials (NWG*4)
//   [16384, 20480)    c2 (L*K)
//   [32768, +1048576) CB_T[l][d][k]  (transposed codebook, 4 MB)
#define WS_C2_OFF  16384
#define WS_CBT_OFF 32768

typedef float v2f __attribute__((ext_vector_type(2)));

// Packed IEEE-rn fp32 FMA, broadcasting one 32-bit half of the R pair:
//  LO: both halves use R.lo ; HI: both halves use R.hi.  Chains stay
//  sequential per code -> bit-identical to scalar __fmaf_rn chains.
//  (HW-verified bit-exact in rounds 5/6.)
#define PKFMA_LO(A, R, C) \
    asm("v_pk_fma_f32 %0, %1, %2, %0 op_sel_hi:[0,1,1]" : "+v"(A) : "v"(R), "v"(C))
#define PKFMA_HI(A, R, C) \
    asm("v_pk_fma_f32 %0, %1, %2, %0 op_sel:[1,0,0]" : "+v"(A) : "v"(R), "v"(C))

// ---------------------------------------------------------------------------
// numpy-mirror row sum-of-squares for 256 contiguous floats (pairwise order).
// ---------------------------------------------------------------------------
__device__ __forceinline__ float np_rowsum_sq(const float* a) {
    float blk[2];
    #pragma unroll
    for (int hb = 0; hb < 2; ++hb) {
        const float* p = a + hb * 128;
        float r8[8][4];
        #pragma unroll
        for (int j = 0; j < 8; ++j) {
            float4 x = *(const float4*)(p + 4 * j);
            r8[j][0] = __fmul_rn(x.x, x.x);
            r8[j][1] = __fmul_rn(x.y, x.y);
            r8[j][2] = __fmul_rn(x.z, x.z);
            r8[j][3] = __fmul_rn(x.w, x.w);
        }
        #pragma unroll
        for (int i = 32; i < 128; i += 32) {
            #pragma unroll
            for (int j = 0; j < 8; ++j) {
                float4 x = *(const float4*)(p + i + 4 * j);
                r8[j][0] = __fadd_rn(r8[j][0], __fmul_rn(x.x, x.x));
                r8[j][1] = __fadd_rn(r8[j][1], __fmul_rn(x.y, x.y));
                r8[j][2] = __fadd_rn(r8[j][2], __fmul_rn(x.z, x.z));
                r8[j][3] = __fadd_rn(r8[j][3], __fmul_rn(x.w, x.w));
            }
        }
        float wv[4];
        #pragma unroll
        for (int L = 0; L < 4; ++L) {
            wv[L] = __fadd_rn(
                __fadd_rn(__fadd_rn(r8[0][L], r8[1][L]), __fadd_rn(r8[2][L], r8[3][L])),
                __fadd_rn(__fadd_rn(r8[4][L], r8[5][L]), __fadd_rn(r8[6][L], r8[7][L])));
        }
        blk[hb] = __fadd_rn(__fadd_rn(wv[0], wv[1]), __fadd_rn(wv[2], wv[3]));
    }
    return __fadd_rn(blk[0], blk[1]);
}

// ---------------------------------------------------------------------------
// prep: c2[l*K + k] = np-order sum of squares of codebook row
// ---------------------------------------------------------------------------
__global__ void prep_kernel(const float* __restrict__ cbks, float* __restrict__ ws) {
    int t = blockIdx.x * 256 + threadIdx.x;
    if (t < Ll * Kk) {
        ws[WS_C2_OFF + t] = np_rowsum_sq(cbks + (size_t)t * Dd);
    }
}

// ---------------------------------------------------------------------------
// transpose: CB_T[l][d][k] = cbks[l][k][d]   (one block per (l,d) row)
// ---------------------------------------------------------------------------
__global__ void transpose_kernel(const float* __restrict__ cbks, float* __restrict__ ws) {
    int ld = blockIdx.x;               // 0 .. L*D-1
    int l  = ld >> 8, d = ld & 255;
    const float* src = cbks + (size_t)l * Kk * Dd + d;
    float* dst = ws + WS_CBT_OFF + (size_t)ld * Kk;
    int k = threadIdx.x;
    #pragma unroll
    for (int kk = 0; kk < Kk; kk += 256)
        dst[kk + k] = src[(size_t)(kk + k) * Dd];
}

// ---------------------------------------------------------------------------
// main residual-VQ kernel: one workgroup owns 32 vectors for all 4 levels
// thread = (tv 0..7, tk 0..31): 4 vecs x 8 codes per kk-block (256 codes)
// packed fp32 FMA, explicitly software-pipelined (named A/B buffers)
// ---------------------------------------------------------------------------
__global__ __launch_bounds__(256, 4) void rvq_kernel(
    const float* __restrict__ ze, const float* __restrict__ cbks,
    float* __restrict__ out, float* __restrict__ ws)
{
    __shared__ float rbuf[TB][Dd + 4];   // 33.3 KB
    __shared__ float r2s[TB];
    __shared__ int   bidx[TB];
    __shared__ float wssq[4];

    const int tid  = threadIdx.x;
    const int wg   = blockIdx.x;
    const int b0   = wg * TB;
    const int lane = tid & 63;
    const int w    = tid >> 6;     // wave id 0..3
    const int tk   = tid & 31;     // code-group lane (32)
    const int tv   = tid >> 5;     // vec-group 0..7
    const int v0   = tv * 4;

    // Load ze tile -> rbuf, and write residual_states[0] = ze
    for (int i = tid; i < TB * Dd / 4; i += 256) {
        int v  = i >> 6;
        int dp = (i & 63) << 2;
        float4 x = *(const float4*)(ze + (size_t)(b0 + v) * Dd + dp);
        *(float4*)&rbuf[v][dp] = x;
        *(float4*)(out + O_RES + (size_t)(b0 + v) * Dd + dp) = x;
    }
    __syncthreads();

    const float* c2  = ws + WS_C2_OFF;
    const float* cbt = ws + WS_CBT_OFF;

    for (int l = 0; l < Ll; ++l) {
        // ---- r2 per vector, numpy pairwise order ----
        if (tid < TB) r2s[tid] = np_rowsum_sq(&rbuf[tid][0]);
        __syncthreads();

        const float* cb   = cbks + (size_t)l * Kk * Dd;     // row-major (gather)
        const float* ctl  = cbt + (size_t)l * Dd * Kk;      // [d][k] (scores)
        const float* c2l  = c2 + l * Kk;

        float bs[4] = {1e30f, 1e30f, 1e30f, 1e30f};
        int   bi[4] = {0, 0, 0, 0};

        for (int kk = 0; kk < Kk; kk += 256) {
            __syncthreads();             // keep block's waves on the same k-slab
            const int kb = kk + tk * 8;  // this thread's 8 codes

            // running pointers: even dims / odd dims, step 2 dims per load call
            const float* cpd0 = ctl + kb;          // dim d   row, codes kb..kb+7
            const float* cpd1 = ctl + kb + 1024;   // dim d+1 row

            v2f acc[4][4];               // [vec][code-pair]
            #pragma unroll
            for (int vi = 0; vi < 4; ++vi)
                #pragma unroll
                for (int p = 0; p < 4; ++p)
                    acc[vi][p] = (v2f)(0.f);

            v2f cA0[4], cA1[4], cB0[4], cB1[4];   // codebook: dims (d, d+1)
            v2f rA[4], rB[4];                     // residual: 4 vecs, dims (d,d+1)

            // ---- load macros: offsets fold into instruction immediates ----
            #define LOADC(C0, C1) do {                                        \
                C0[0] = *(const v2f*)(cpd0 + 0);                              \
                C0[1] = *(const v2f*)(cpd0 + 2);                              \
                C0[2] = *(const v2f*)(cpd0 + 4);                              \
                C0[3] = *(const v2f*)(cpd0 + 6);                              \
                C1[0] = *(const v2f*)(cpd1 + 0);                              \
                C1[1] = *(const v2f*)(cpd1 + 2);                              \
                C1[2] = *(const v2f*)(cpd1 + 4);                              \
                C1[3] = *(const v2f*)(cpd1 + 6);                              \
                cpd0 += 2048; cpd1 += 2048; } while (0)
            #define LOADR(R, dd) do {                                         \
                R[0] = *(const v2f*)&rbuf[v0 + 0][dd];                        \
                R[1] = *(const v2f*)&rbuf[v0 + 1][dd];                        \
                R[2] = *(const v2f*)&rbuf[v0 + 2][dd];                        \
                R[3] = *(const v2f*)&rbuf[v0 + 3][dd];  } while (0)
            // FMA over 2 dims: LO = dim d (R.lo), HI = dim d+1 (R.hi)
            #define FMA2(C0, C1, R) do {                                      \
                _Pragma("unroll")                                             \
                for (int vi = 0; vi < 4; ++vi) {                              \
                    _Pragma("unroll")                                         \
                    for (int p = 0; p < 4; ++p) {                             \
                        PKFMA_LO(acc[vi][p], R[vi], C0[p]);                   \
                        PKFMA_HI(acc[vi][p], R[vi], C1[p]);                   \
                    }                                                         \
                } } while (0)

            // ---- software-pipelined d-loop (last iteration peeled) ----
            LOADC(cA0, cA1); LOADR(rA, 0);
            for (int d = 0; d < Dd - 4; d += 4) {
                LOADC(cB0, cB1); LOADR(rB, d + 2);
                FMA2(cA0, cA1, rA);
                LOADC(cA0, cA1); LOADR(rA, d + 4);
                FMA2(cB0, cB1, rB);
            }
            LOADC(cB0, cB1); LOADR(rB, Dd - 2);
            FMA2(cA0, cA1, rA);
            FMA2(cB0, cB1, rB);

            #undef LOADC
            #undef LOADR
            #undef FMA2

            // scores + running argmin (codes ascending: strict < keeps lowest)
            #pragma unroll
            for (int c = 0; c < 8; ++c) {
                float c2v = c2l[kb + c];
                int   k   = kb + c;
                #pragma unroll
                for (int vi = 0; vi < 4; ++vi) {
                    float dotv = acc[vi][c >> 1][c & 1];
                    float t1 = __fadd_rn(r2s[v0 + vi], c2v);
                    float s  = __fsub_rn(t1, 2.0f * dotv);
                    if (s < bs[vi]) { bs[vi] = s; bi[vi] = k; }
                }
            }
        }

        // ---- reduce argmin across the 32 tk lanes (tie -> lower index) ----
        #pragma unroll
        for (int m = 1; m < 32; m <<= 1) {
            #pragma unroll
            for (int vi = 0; vi < 4; ++vi) {
                float os = __shfl_xor(bs[vi], m);
                int   oi = __shfl_xor(bi[vi], m);
                if (os < bs[vi] || (os == bs[vi] && oi < bi[vi])) {
                    bs[vi] = os; bi[vi] = oi;
                }
            }
        }
        if (tk == 0) {
            #pragma unroll
            for (int vi = 0; vi < 4; ++vi) {
                bidx[v0 + vi] = bi[vi];
                out[O_IDX + (size_t)(b0 + v0 + vi) * Ll + l] = (float)bi[vi];
            }
        }
        __syncthreads();

        // ---- gather chosen codes, update residual, emit outputs ----
        float ssq = 0.f;
        for (int v = w * 8; v < w * 8 + 8; ++v) {
            int idx = bidx[v];
            const float4 q = *(const float4*)(cb + (size_t)idx * Dd + (lane << 2));
            float4 r = *(const float4*)&rbuf[v][lane << 2];
            float4 nr = make_float4(r.x - q.x, r.y - q.y, r.z - q.z, r.w - q.w);
            *(float4*)&rbuf[v][lane << 2] = nr;
            size_t gb = (size_t)(b0 + v);
            *(float4*)(out + O_QSTK + ((gb * Ll) + l) * Dd + (lane << 2)) = q;
            *(float4*)(out + O_RES + ((size_t)(l + 1) * Bsz + gb) * Dd + (lane << 2)) = nr;
            ssq += nr.x * nr.x + nr.y * nr.y + nr.z * nr.z + nr.w * nr.w;
        }
        #pragma unroll
        for (int m = 32; m; m >>= 1) ssq += __shfl_xor(ssq, m);
        if (lane == 0) wssq[w] = ssq;
        __syncthreads();
        if (tid == 0) ws[wg * 4 + l] = wssq[0] + wssq[1] + wssq[2] + wssq[3];
    }

    // ---- quantized_sum = ze - final_residual; qspace = ze + (qsum - ze) ----
    for (int i = tid; i < TB * Dd / 4; i += 256) {
        int v  = i >> 6;
        int dp = (i & 63) << 2;
        size_t gb = (size_t)(b0 + v);
        float4 z = *(const float4*)(ze + gb * Dd + dp);
        float4 r = *(const float4*)&rbuf[v][dp];
        float4 qs = make_float4(z.x - r.x, z.y - r.y, z.z - r.z, z.w - r.w);
        *(float4*)(out + O_QSUM + gb * Dd + dp) = qs;
        float4 qq = make_float4(z.x + (qs.x - z.x), z.y + (qs.y - z.y),
                                z.z + (qs.z - z.z), z.w + (qs.w - z.w));
        *(float4*)(out + O_QSQ + gb * Dd + dp) = qq;
    }
}

// ---------------------------------------------------------------------------
// loss: deterministic reduction of per-WG partials -> 3 scalars
// ---------------------------------------------------------------------------
__global__ void loss_kernel(const float* __restrict__ ws, float* __restrict__ out) {
    __shared__ float red[Ll * 4];
    int tid = threadIdx.x;
    int lane = tid & 63, w = tid >> 6;
    for (int l = 0; l < Ll; ++l) {
        float s = 0.f;
        for (int i = tid; i < NWG; i += 256) s += ws[i * 4 + l];
        #pragma unroll
        for (int m = 32; m; m >>= 1) s += __shfl_xor(s, m);
        if (lane == 0) red[l * 4 + w] = s;
    }
    __syncthreads();
    if (tid == 0) {
        float tot = 0.f;
        for (int l = 0; l < Ll; ++l)
            tot += red[l * 4 + 0] + red[l * 4 + 1] + red[l * 4 + 2] + red[l * 4 + 3];
        float cm = tot / (float)((size_t)Ll * Bsz * Dd);
        out[O_LOSS + 0] = cm;                    // commitment_loss
        out[O_LOSS + 1] = cm;                    // codebook_loss
        out[O_LOSS + 2] = 0.25f * cm + cm;       // quantization_loss
    }
}

extern "C" void kernel_launch(void* const* d_in, const int* in_sizes, int n_in,
                              void* d_out, int out_size, void* d_ws, size_t ws_size,
                              hipStream_t stream) {
    (void)in_sizes; (void)n_in; (void)out_size; (void)ws_size;
    const float* ze   = (const float*)d_in[0];
    const float* cbks = (const float*)d_in[1];
    float* out = (float*)d_out;
    float* ws  = (float*)d_ws;

    hipLaunchKernelGGL(prep_kernel, dim3(16), dim3(256), 0, stream, cbks, ws);
    hipLaunchKernelGGL(transpose_kernel, dim3(Ll * Dd), dim3(256), 0, stream, cbks, ws);
    hipLaunchKernelGGL(rvq_kernel, dim3(NWG), dim3(256), 0, stream, ze, cbks, out, ws);
    hipLaunchKernelGGL(loss_kernel, dim3(1), dim3(256), 0, stream, ws, out);
}

// Round 8
// 1990.582 us; speedup vs baseline: 7.2706x; 2.3159x over previous
//
#include <hip/hip_runtime.h>

// Problem constants
#define Bsz 131072
#define Dd  256
#define Ll  4
#define Kk  1024
#define TB  32                 // vectors per workgroup
#define NWG (Bsz / TB)         // 4096
#define CAP 2048               // candidate list capacity per WG-level
#define MARGIN 0.05f           // >> worst-case bf16 screening error (~0.026)

// Output layout (element offsets into float32 d_out, concat in return order)
#define O_IDX   0ULL                                   // indices      [B][L]
#define O_QSTK  524288ULL                              // quant_stack  [B][L][D]
#define O_QSUM  (O_QSTK + (size_t)Bsz * Ll * Dd)       // quant_sum    [B][D]
#define O_QSQ   (O_QSUM + (size_t)Bsz * Dd)            // quant_sum_qs [B][D]
#define O_RES   (O_QSQ  + (size_t)Bsz * Dd)            // res_states   [L+1][B][D]
#define O_LOSS  (O_RES  + (size_t)(Ll + 1) * Bsz * Dd) // 3 scalars

// ws layout: [0,16384) per-WG/level ssq partials; [16384,20480) c2 (np-exact);
// float-offset 32768: bf16 codebook copy CBH[l][k][d] (ushort, 2 MB)
#define WS_C2_OFF  16384
#define WS_CBH_OFF 32768

typedef short v8s __attribute__((ext_vector_type(8)));
typedef float v4f __attribute__((ext_vector_type(4)));

__device__ __forceinline__ unsigned short f2bf(float f) {   // RNE f32->bf16
    unsigned u = __float_as_uint(f);
    return (unsigned short)((u + 0x7fffu + ((u >> 16) & 1u)) >> 16);
}

// ---------------------------------------------------------------------------
// numpy-mirror row sum-of-squares for 256 contiguous floats (pairwise order).
// ---------------------------------------------------------------------------
__device__ __forceinline__ float np_rowsum_sq(const float* a) {
    float blk[2];
    #pragma unroll
    for (int hb = 0; hb < 2; ++hb) {
        const float* p = a + hb * 128;
        float r8[8][4];
        #pragma unroll
        for (int j = 0; j < 8; ++j) {
            float4 x = *(const float4*)(p + 4 * j);
            r8[j][0] = __fmul_rn(x.x, x.x);
            r8[j][1] = __fmul_rn(x.y, x.y);
            r8[j][2] = __fmul_rn(x.z, x.z);
            r8[j][3] = __fmul_rn(x.w, x.w);
        }
        #pragma unroll
        for (int i = 32; i < 128; i += 32) {
            #pragma unroll
            for (int j = 0; j < 8; ++j) {
                float4 x = *(const float4*)(p + i + 4 * j);
                r8[j][0] = __fadd_rn(r8[j][0], __fmul_rn(x.x, x.x));
                r8[j][1] = __fadd_rn(r8[j][1], __fmul_rn(x.y, x.y));
                r8[j][2] = __fadd_rn(r8[j][2], __fmul_rn(x.z, x.z));
                r8[j][3] = __fadd_rn(r8[j][3], __fmul_rn(x.w, x.w));
            }
        }
        float wv[4];
        #pragma unroll
        for (int L = 0; L < 4; ++L) {
            wv[L] = __fadd_rn(
                __fadd_rn(__fadd_rn(r8[0][L], r8[1][L]), __fadd_rn(r8[2][L], r8[3][L])),
                __fadd_rn(__fadd_rn(r8[4][L], r8[5][L]), __fadd_rn(r8[6][L], r8[7][L])));
        }
        blk[hb] = __fadd_rn(__fadd_rn(wv[0], wv[1]), __fadd_rn(wv[2], wv[3]));
    }
    return __fadd_rn(blk[0], blk[1]);
}

__global__ void prep_kernel(const float* __restrict__ cbks, float* __restrict__ ws) {
    int t = blockIdx.x * 256 + threadIdx.x;
    if (t < Ll * Kk) ws[WS_C2_OFF + t] = np_rowsum_sq(cbks + (size_t)t * Dd);
}

// bf16 copy of codebook, same [l][k][d] layout (k-contig d = MFMA K-dim)
__global__ void cvt_kernel(const float* __restrict__ cbks, float* __restrict__ ws) {
    unsigned short* cbh = (unsigned short*)(ws + WS_CBH_OFF);
    int i = (blockIdx.x * 256 + threadIdx.x) * 4;
    float4 x = *(const float4*)(cbks + i);
    ushort4 y;
    y.x = f2bf(x.x); y.y = f2bf(x.y); y.z = f2bf(x.z); y.w = f2bf(x.w);
    *(ushort4*)(cbh + i) = y;
}

// ---------------------------------------------------------------------------
// main kernel: WG owns 32 vectors through all 4 levels.
// Per level: bf16-MFMA screening -> candidate list -> exact np rescore.
// ---------------------------------------------------------------------------
__global__ __launch_bounds__(256, 2) void rvq_kernel(
    const float* __restrict__ ze, const float* __restrict__ cbks,
    float* __restrict__ out, float* __restrict__ ws)
{
    __shared__ float  rbuf[TB][Dd + 4];          // fp32 residual (exact)
    __shared__ unsigned short rb16[TB * Dd];     // bf16 residual, XOR-swizzled
    __shared__ float  r2s[TB];
    __shared__ unsigned long long best64[TB];
    __shared__ float  mrun[4][TB];               // per-wave running row-min
    __shared__ int    clist[CAP];
    __shared__ int    ccount;
    __shared__ int    bidx[TB];
    __shared__ float  wssq[4];

    const int tid  = threadIdx.x;
    const int wg   = blockIdx.x;
    const int b0   = wg * TB;
    const int lane = tid & 63;
    const int w    = tid >> 6;     // wave id 0..3
    const int lrow = lane & 15;    // MFMA row/col lane index
    const int lk   = lane >> 4;    // MFMA k-group

    const float* c2  = ws + WS_C2_OFF;
    const unsigned short* cbh = (const unsigned short*)(ws + WS_CBH_OFF);

    // Load ze tile -> rbuf, write residual_states[0] = ze
    for (int i = tid; i < TB * Dd / 4; i += 256) {
        int v  = i >> 6;
        int dp = (i & 63) << 2;
        float4 x = *(const float4*)(ze + (size_t)(b0 + v) * Dd + dp);
        *(float4*)&rbuf[v][dp] = x;
        *(float4*)(out + O_RES + (size_t)(b0 + v) * Dd + dp) = x;
    }
    __syncthreads();

    for (int l = 0; l < Ll; ++l) {
        // ---- per-level init + exact r2 + bf16 residual copy ----
        if (tid < TB) { r2s[tid] = np_rowsum_sq(&rbuf[tid][0]); best64[tid] = ~0ull; }
        if (tid < 128) mrun[tid >> 5][tid & 31] = 1e30f;
        if (tid == 0) ccount = 0;
        for (int gi = tid; gi < TB * 32; gi += 256) {   // 32 granules x 8 bf16 per row
            int v = gi >> 5, g = gi & 31;
            float4 x0 = *(const float4*)&rbuf[v][g * 8];
            float4 x1 = *(const float4*)&rbuf[v][g * 8 + 4];
            v8s o;
            o[0] = (short)f2bf(x0.x); o[1] = (short)f2bf(x0.y);
            o[2] = (short)f2bf(x0.z); o[3] = (short)f2bf(x0.w);
            o[4] = (short)f2bf(x1.x); o[5] = (short)f2bf(x1.y);
            o[6] = (short)f2bf(x1.z); o[7] = (short)f2bf(x1.w);
            *(v8s*)&rb16[v * Dd + ((g ^ (v & 7)) << 3)] = o;   // bank swizzle
        }
        __syncthreads();

        const unsigned short* cbh_l = cbh + (size_t)l * Kk * Dd;
        const float* c2l = c2 + l * Kk;
        const float* cb  = cbks + (size_t)l * Kk * Dd;

        // ---- MFMA screening: wave w covers codes [w*256, w*256+256) ----
        const unsigned short* ap0 = &rb16[(size_t)lrow * Dd];
        const unsigned short* ap1 = &rb16[(size_t)(lrow + 16) * Dd];
        const int axor = lrow & 7;   // (lrow+16)&7 identical

        for (int sc = 0; sc < 4; ++sc) {
            const int cbase = w * 256 + sc * 64;
            v4f acc[2][4];
            #pragma unroll
            for (int rt = 0; rt < 2; ++rt)
                #pragma unroll
                for (int ct = 0; ct < 4; ++ct) acc[rt][ct] = (v4f)(0.f);

            const unsigned short* bp[4];
            #pragma unroll
            for (int ct = 0; ct < 4; ++ct)
                bp[ct] = cbh_l + (size_t)(cbase + ct * 16 + lrow) * Dd + lk * 8;

            #pragma unroll
            for (int ks = 0; ks < 8; ++ks) {
                int aoff = (((ks * 4 + lk) ^ axor) << 3);
                v8s a0 = *(const v8s*)(ap0 + aoff);
                v8s a1 = *(const v8s*)(ap1 + aoff);
                #pragma unroll
                for (int ct = 0; ct < 4; ++ct) {
                    v8s b = *(const v8s*)(bp[ct] + ks * 32);
                    acc[0][ct] = __builtin_amdgcn_mfma_f32_16x16x32_bf16(a0, b, acc[0][ct], 0, 0, 0);
                    acc[1][ct] = __builtin_amdgcn_mfma_f32_16x16x32_bf16(a1, b, acc[1][ct], 0, 0, 0);
                }
            }

            float c2v[4];
            #pragma unroll
            for (int ct = 0; ct < 4; ++ct) c2v[ct] = c2l[cbase + ct * 16 + lrow];

            // candidate collection: C-layout col=lane&15, row=(lane>>4)*4+reg
            #pragma unroll
            for (int rt = 0; rt < 2; ++rt) {
                #pragma unroll
                for (int reg = 0; reg < 4; ++reg) {
                    int row = rt * 16 + lk * 4 + reg;
                    float t0 = c2v[0] - 2.f * acc[rt][0][reg];
                    float t1 = c2v[1] - 2.f * acc[rt][1][reg];
                    float t2 = c2v[2] - 2.f * acc[rt][2][reg];
                    float t3 = c2v[3] - 2.f * acc[rt][3][reg];
                    float pm = fminf(fminf(t0, t1), fminf(t2, t3));
                    pm = fminf(pm, __shfl_xor(pm, 1));
                    pm = fminf(pm, __shfl_xor(pm, 2));
                    pm = fminf(pm, __shfl_xor(pm, 4));
                    pm = fminf(pm, __shfl_xor(pm, 8));
                    float nm = fminf(mrun[w][row], pm);
                    mrun[w][row] = nm;
                    float th = nm + MARGIN;
                    if (t0 < th) { int p = atomicAdd(&ccount, 1); if (p < CAP) clist[p] = (row << 10) | (cbase + 0 * 16 + lrow); }
                    if (t1 < th) { int p = atomicAdd(&ccount, 1); if (p < CAP) clist[p] = (row << 10) | (cbase + 1 * 16 + lrow); }
                    if (t2 < th) { int p = atomicAdd(&ccount, 1); if (p < CAP) clist[p] = (row << 10) | (cbase + 2 * 16 + lrow); }
                    if (t3 < th) { int p = atomicAdd(&ccount, 1); if (p < CAP) clist[p] = (row << 10) | (cbase + 3 * 16 + lrow); }
                }
            }
        }
        __syncthreads();

        // ---- exact np-order rescore of candidates (fallback: all pairs) ----
        {
            int cnt = ccount;
            int total = (cnt <= CAP) ? cnt : (TB * Kk);
            for (int ci = tid; ci < total; ci += 256) {
                int row, code;
                if (cnt <= CAP) { int rc = clist[ci]; row = rc >> 10; code = rc & 1023; }
                else            { row = ci >> 10; code = ci & 1023; }
                const float* cp = cb + (size_t)code * Dd;
                const float* rp = &rbuf[row][0];
                float a = 0.f;
                #pragma unroll 4
                for (int d = 0; d < Dd; d += 4) {
                    float4 cv = *(const float4*)(cp + d);
                    a = __fmaf_rn(rp[d + 0], cv.x, a);
                    a = __fmaf_rn(rp[d + 1], cv.y, a);
                    a = __fmaf_rn(rp[d + 2], cv.z, a);
                    a = __fmaf_rn(rp[d + 3], cv.w, a);
                }
                float s = __fsub_rn(__fadd_rn(r2s[row], c2l[code]), 2.0f * a);
                unsigned long long pk =
                    (((unsigned long long)__float_as_uint(s)) << 32) | (unsigned)code;
                atomicMin(&best64[row], pk);
            }
        }
        __syncthreads();

        if (tid < TB) {
            int code = (int)(best64[tid] & 0xffffffffu);
            bidx[tid] = code;
            out[O_IDX + (size_t)(b0 + tid) * Ll + l] = (float)code;
        }
        __syncthreads();

        // ---- gather chosen codes, update residual, emit outputs (exact) ----
        float ssq = 0.f;
        for (int v = w * 8; v < w * 8 + 8; ++v) {
            int idx = bidx[v];
            const float4 q = *(const float4*)(cb + (size_t)idx * Dd + (lane << 2));
            float4 r = *(const float4*)&rbuf[v][lane << 2];
            float4 nr = make_float4(r.x - q.x, r.y - q.y, r.z - q.z, r.w - q.w);
            *(float4*)&rbuf[v][lane << 2] = nr;
            size_t gb = (size_t)(b0 + v);
            *(float4*)(out + O_QSTK + ((gb * Ll) + l) * Dd + (lane << 2)) = q;
            *(float4*)(out + O_RES + ((size_t)(l + 1) * Bsz + gb) * Dd + (lane << 2)) = nr;
            ssq += nr.x * nr.x + nr.y * nr.y + nr.z * nr.z + nr.w * nr.w;
        }
        #pragma unroll
        for (int m = 32; m; m >>= 1) ssq += __shfl_xor(ssq, m);
        if (lane == 0) wssq[w] = ssq;
        __syncthreads();
        if (tid == 0) ws[wg * 4 + l] = wssq[0] + wssq[1] + wssq[2] + wssq[3];
        __syncthreads();
    }

    // ---- quantized_sum = ze - final_residual; qspace = ze + (qsum - ze) ----
    for (int i = tid; i < TB * Dd / 4; i += 256) {
        int v  = i >> 6;
        int dp = (i & 63) << 2;
        size_t gb = (size_t)(b0 + v);
        float4 z = *(const float4*)(ze + gb * Dd + dp);
        float4 r = *(const float4*)&rbuf[v][dp];
        float4 qs = make_float4(z.x - r.x, z.y - r.y, z.z - r.z, z.w - r.w);
        *(float4*)(out + O_QSUM + gb * Dd + dp) = qs;
        float4 qq = make_float4(z.x + (qs.x - z.x), z.y + (qs.y - z.y),
                                z.z + (qs.z - z.z), z.w + (qs.w - z.w));
        *(float4*)(out + O_QSQ + gb * Dd + dp) = qq;
    }
}

// ---------------------------------------------------------------------------
// loss: deterministic reduction of per-WG partials -> 3 scalars
// ---------------------------------------------------------------------------
__global__ void loss_kernel(const float* __restrict__ ws, float* __restrict__ out) {
    __shared__ float red[Ll * 4];
    int tid = threadIdx.x;
    int lane = tid & 63, w = tid >> 6;
    for (int l = 0; l < Ll; ++l) {
        float s = 0.f;
        for (int i = tid; i < NWG; i += 256) s += ws[i * 4 + l];
        #pragma unroll
        for (int m = 32; m; m >>= 1) s += __shfl_xor(s, m);
        if (lane == 0) red[l * 4 + w] = s;
    }
    __syncthreads();
    if (tid == 0) {
        float tot = 0.f;
        for (int l = 0; l < Ll; ++l)
            tot += red[l * 4 + 0] + red[l * 4 + 1] + red[l * 4 + 2] + red[l * 4 + 3];
        float cm = tot / (float)((size_t)Ll * Bsz * Dd);
        out[O_LOSS + 0] = cm;                    // commitment_loss
        out[O_LOSS + 1] = cm;                    // codebook_loss
        out[O_LOSS + 2] = 0.25f * cm + cm;       // quantization_loss
    }
}

extern "C" void kernel_launch(void* const* d_in, const int* in_sizes, int n_in,
                              void* d_out, int out_size, void* d_ws, size_t ws_size,
                              hipStream_t stream) {
    (void)in_sizes; (void)n_in; (void)out_size; (void)ws_size;
    const float* ze   = (const float*)d_in[0];
    const float* cbks = (const float*)d_in[1];
    float* out = (float*)d_out;
    float* ws  = (float*)d_ws;

    hipLaunchKernelGGL(prep_kernel, dim3(16), dim3(256), 0, stream, cbks, ws);
    hipLaunchKernelGGL(cvt_kernel, dim3(Ll * Kk * Dd / 1024), dim3(256), 0, stream, cbks, ws);
    hipLaunchKernelGGL(rvq_kernel, dim3(NWG), dim3(256), 0, stream, ze, cbks, out, ws);
    hipLaunchKernelGGL(loss_kernel, dim3(1), dim3(256), 0, stream, ws, out);
}